// Round 1
// baseline (2025.087 us; speedup 1.0000x reference)
//
#include <hip/hip_runtime.h>
#include <math.h>

#define Bn 4
#define Nn 512
#define Dn 128
#define Hn 64

__device__ __forceinline__ float silu_f(float x) {
    return x * (1.0f / (1.0f + __expf(-x)));
}

// ---------------------------------------------------------------------------
// Kernel 1: fused radial MLP + mask/softmask/adjacency weighting + contraction
// with neighbor embeddings.  One block per (b,i) row; 256 threads.
//
// neighbor_feats[b,i,d] = sum_j w(b,i,j) * (h2(b,i,j,:)·rW3[:,d] + rb3[d])
//                                       * neigh_tab[atoms[b,j], d]
// where w = adj(no diag) * mask_j * softmask, h2 = LN(silu(LN(silu(...))@rW2))
// ---------------------------------------------------------------------------
struct __align__(16) K1Smem {
    float rW2t[Hn][68];   // transposed rW2: [k2][k], padded rows (272B, 16B-aligned)
    float wh2[32][68];    // w-scaled normalized h2 for a 32-j sub-tile
    float rW1s[Hn], rb1s[Hn], rg1s[Hn], rb2s[Hn], rg2s[Hn];
    float wsub[32];
    float accpart[256];
    int   atomsS[Nn];
};

__global__ __launch_bounds__(256, 2)
void k1_neighbor_feats(const int* __restrict__ atoms,
                       const float* __restrict__ rel_dist,
                       const int* __restrict__ adj_mat,
                       const int* __restrict__ mask,
                       const float* __restrict__ soft,
                       const float* __restrict__ neigh_tab,
                       const float* __restrict__ rW1, const float* __restrict__ rb1,
                       const float* __restrict__ rg1,
                       const float* __restrict__ rW2, const float* __restrict__ rb2,
                       const float* __restrict__ rg2,
                       const float* __restrict__ rW3, const float* __restrict__ rb3,
                       float* __restrict__ nf)
{
    __shared__ K1Smem sm;
    const int t  = threadIdx.x;
    const int bi = blockIdx.x;      // b*N + i
    const int b  = bi >> 9;
    const int i  = bi & 511;

    // ---- stage weights ----
    for (int idx = t; idx < Hn * Hn; idx += 256) {
        const int k  = idx >> 6;    // row of rW2
        const int k2 = idx & 63;    // col of rW2
        sm.rW2t[k2][k] = rW2[idx];
    }
    if (t < Hn) {
        sm.rW1s[t] = rW1[t];
        sm.rb1s[t] = rb1[t];
        sm.rg1s[t] = rg1[t];
        sm.rb2s[t] = rb2[t];
        sm.rg2s[t] = rg2[t];
    }
    for (int j = t; j < Nn; j += 256) sm.atomsS[j] = atoms[b * Nn + j];

    const int d     = t & 127;
    const int jhalf = t >> 7;
    const float rb3d = rb3[d];
    const int rowbase = bi * Nn;    // = b*N*N + i*N

    float acc = 0.0f;
    __syncthreads();

    for (int jt = 0; jt < 2; ++jt) {
        const int jme = jt * 256 + t;

        // ---- phase A: per-thread j MLP ----
        const float dist = rel_dist[rowbase + jme];
        const int   adjv = adj_mat[rowbase + jme];
        const int   mk   = mask[b * Nn + jme];
        const float w = (adjv != 0 && mk != 0 && jme != i) ? soft[rowbase + jme] : 0.0f;

        // layer 1: silu(dist*rW1 + rb1) then LN(rg1)
        float h1n[Hn];
        float s1 = 0.f, s2 = 0.f;
        #pragma unroll
        for (int k = 0; k < Hn; ++k) {
            const float v = silu_f(dist * sm.rW1s[k] + sm.rb1s[k]);
            h1n[k] = v; s1 += v; s2 += v * v;
        }
        float m  = s1 * (1.0f / 64.0f);
        float vr = s2 * (1.0f / 64.0f) - m * m;
        float rs = rsqrtf(vr + 1e-5f);
        #pragma unroll
        for (int k = 0; k < Hn; ++k) h1n[k] = (h1n[k] - m) * rs * sm.rg1s[k];

        // layer 2: silu(h1n @ rW2 + rb2) then LN(rg2); fold weight w in
        float h2[Hn];
        float t1 = 0.f, t2 = 0.f;
        #pragma unroll
        for (int k2 = 0; k2 < Hn; ++k2) {
            float p0 = 0.f, p1 = 0.f, p2 = 0.f, p3 = 0.f;
            #pragma unroll
            for (int k = 0; k < Hn; k += 4) {
                const float4 wv = *(const float4*)&sm.rW2t[k2][k];  // LDS broadcast b128
                p0 += h1n[k + 0] * wv.x;
                p1 += h1n[k + 1] * wv.y;
                p2 += h1n[k + 2] * wv.z;
                p3 += h1n[k + 3] * wv.w;
            }
            const float v = silu_f((p0 + p1) + (p2 + p3) + sm.rb2s[k2]);
            h2[k2] = v; t1 += v; t2 += v * v;
        }
        m  = t1 * (1.0f / 64.0f);
        vr = t2 * (1.0f / 64.0f) - m * m;
        rs = rsqrtf(vr + 1e-5f);
        #pragma unroll
        for (int k2 = 0; k2 < Hn; ++k2) h2[k2] = w * ((h2[k2] - m) * rs * sm.rg2s[k2]);

        // reload rW3 column for this thread's d (keeps VGPR peak down;
        // coalesced, L1/L2-hot)
        float rw3c[Hn];
        #pragma unroll
        for (int k = 0; k < Hn; ++k) rw3c[k] = rW3[k * Dn + d];

        // ---- sub-tiles of 32 j: publish wh2, all threads contract ----
        for (int sub = 0; sub < 8; ++sub) {
            if ((t >> 5) == sub) {
                const int jj = t & 31;
                #pragma unroll
                for (int k = 0; k < Hn; k += 4) {
                    *(float4*)&sm.wh2[jj][k] =
                        make_float4(h2[k], h2[k + 1], h2[k + 2], h2[k + 3]);
                }
                sm.wsub[jj] = w;
            }
            __syncthreads();

            const int j0 = jt * 256 + sub * 32;
            #pragma unroll
            for (int jj = 0; jj < 16; ++jj) {
                const int lr = jhalf * 16 + jj;       // row in wh2
                const int j  = j0 + lr;               // global j
                float p0 = 0.f, p1 = 0.f, p2 = 0.f, p3 = 0.f;
                #pragma unroll
                for (int k = 0; k < Hn; k += 4) {
                    const float4 hv = *(const float4*)&sm.wh2[lr][k];  // broadcast
                    p0 += hv.x * rw3c[k + 0];
                    p1 += hv.y * rw3c[k + 1];
                    p2 += hv.z * rw3c[k + 2];
                    p3 += hv.w * rw3c[k + 3];
                }
                const float wj   = sm.wsub[lr];
                const float nval = neigh_tab[sm.atomsS[j] * Dn + d];
                acc += ((p0 + p1) + (p2 + p3) + wj * rb3d) * nval;
            }
            __syncthreads();
        }
    }

    // ---- combine the two jhalf partials, write neighbor_feats ----
    sm.accpart[t] = acc;
    __syncthreads();
    if (t < 128) {
        nf[bi * Dn + t] = sm.accpart[t] + sm.accpart[t + 128];
    }
}

// ---------------------------------------------------------------------------
// Kernel 2: node MLP.  x = [embeds, nf] (256) -> Linear -> LN -> silu -> Linear
// One block per (b,i); 128 threads (one per output d).
// ---------------------------------------------------------------------------
__global__ __launch_bounds__(128)
void k2_node_mlp(const int* __restrict__ atoms,
                 const float* __restrict__ atom_tab,
                 const float* __restrict__ nf,
                 const float* __restrict__ nW1, const float* __restrict__ nb1,
                 const float* __restrict__ ng,
                 const float* __restrict__ nW2, const float* __restrict__ nb2,
                 float* __restrict__ out)
{
    __shared__ float xs[256];
    __shared__ float r1[2], r2[2];
    __shared__ float x2[128];

    const int t  = threadIdx.x;
    const int bi = blockIdx.x;
    const int a  = atoms[bi];

    xs[t]       = atom_tab[a * Dn + t];
    xs[128 + t] = nf[bi * Dn + t];
    __syncthreads();

    float p0 = 0.f, p1 = 0.f, p2 = 0.f, p3 = 0.f;
    #pragma unroll 4
    for (int c = 0; c < 256; c += 4) {
        p0 += xs[c + 0] * nW1[(c + 0) * Dn + t];
        p1 += xs[c + 1] * nW1[(c + 1) * Dn + t];
        p2 += xs[c + 2] * nW1[(c + 2) * Dn + t];
        p3 += xs[c + 3] * nW1[(c + 3) * Dn + t];
    }
    const float s = (p0 + p1) + (p2 + p3) + nb1[t];

    // LN over 128 (2 waves): wave shuffle reduce + LDS combine
    float a1 = s, a2 = s * s;
    #pragma unroll
    for (int off = 32; off > 0; off >>= 1) {
        a1 += __shfl_down(a1, off);
        a2 += __shfl_down(a2, off);
    }
    const int wid = t >> 6;
    if ((t & 63) == 0) { r1[wid] = a1; r2[wid] = a2; }
    __syncthreads();
    const float S1 = r1[0] + r1[1];
    const float S2 = r2[0] + r2[1];
    const float m  = S1 * (1.0f / 128.0f);
    const float vr = S2 * (1.0f / 128.0f) - m * m;
    const float rs = rsqrtf(vr + 1e-5f);
    const float y  = silu_f((s - m) * rs * ng[t]);   // LN first, THEN silu

    x2[t] = y;
    __syncthreads();

    float q0 = 0.f, q1 = 0.f, q2 = 0.f, q3 = 0.f;
    #pragma unroll 4
    for (int c = 0; c < 128; c += 4) {
        q0 += x2[c + 0] * nW2[(c + 0) * Dn + t];
        q1 += x2[c + 1] * nW2[(c + 1) * Dn + t];
        q2 += x2[c + 2] * nW2[(c + 2) * Dn + t];
        q3 += x2[c + 3] * nW2[(c + 3) * Dn + t];
    }
    out[bi * Dn + t] = (q0 + q1) + (q2 + q3) + nb2[t];
}

// ---------------------------------------------------------------------------
extern "C" void kernel_launch(void* const* d_in, const int* in_sizes, int n_in,
                              void* d_out, int out_size, void* d_ws, size_t ws_size,
                              hipStream_t stream)
{
    (void)in_sizes; (void)n_in; (void)out_size; (void)ws_size;

    const int*   atoms = (const int*)d_in[0];
    const float* rel   = (const float*)d_in[1];
    const int*   adj   = (const int*)d_in[2];
    const int*   mask  = (const int*)d_in[3];
    const float* soft  = (const float*)d_in[4];
    const float* atab  = (const float*)d_in[5];
    const float* ntab  = (const float*)d_in[6];
    const float* rW1   = (const float*)d_in[7];
    const float* rb1   = (const float*)d_in[8];
    const float* rg1   = (const float*)d_in[9];
    const float* rW2   = (const float*)d_in[10];
    const float* rb2   = (const float*)d_in[11];
    const float* rg2   = (const float*)d_in[12];
    const float* rW3   = (const float*)d_in[13];
    const float* rb3   = (const float*)d_in[14];
    const float* nW1   = (const float*)d_in[15];
    const float* nb1   = (const float*)d_in[16];
    const float* ng    = (const float*)d_in[17];
    const float* nW2   = (const float*)d_in[18];
    const float* nb2   = (const float*)d_in[19];

    float* nf  = (float*)d_ws;      // [B*N, D] neighbor feats scratch (1 MB)
    float* out = (float*)d_out;

    hipLaunchKernelGGL(k1_neighbor_feats, dim3(Bn * Nn), dim3(256), 0, stream,
                       atoms, rel, adj, mask, soft, ntab,
                       rW1, rb1, rg1, rW2, rb2, rg2, rW3, rb3, nf);
    hipLaunchKernelGGL(k2_node_mlp, dim3(Bn * Nn), dim3(128), 0, stream,
                       atoms, atab, nf, nW1, nb1, ng, nW2, nb2, out);
}

// Round 2
// 1097.369 us; speedup vs baseline: 1.8454x; 1.8454x over previous
//
#include <hip/hip_runtime.h>
#include <math.h>

#define Bn 4
#define Nn 512
#define Dn 128
#define Hn 64
#define JT 128      // j-tile size
#define NT 4        // Nn / JT

__device__ __forceinline__ float silu_f(float x) {
    return x * (1.0f / (1.0f + __expf(-x)));
}

// ---------------------------------------------------------------------------
// Kernel 1: fused radial MLP + weighting + contraction with neighbor embeds.
// One block per (b,i); 256 threads; j processed in 4 tiles of 128.
//
// Phase A (per tile): thread (jloc = t&127, half = t>>7) computes the radial
//   MLP for j = jt*128+jloc; the 64 h2 outputs are split across the 2 halves
//   (32 each) to cap live registers (h1n[64] + h2[32] ~ 110 VGPRs, no spill).
//   LN stats for h2 are combined across the half-pair through LDS.
//   Result w * LN(h2) is published to LDS tile wh2[128][68].
// Phase B (per tile): thread (d2 = t&63, kh = (t>>6)&1, jh = t>>7) owns
//   2 output columns {2*d2, 2*d2+1}, a 32-wide k-slice, and 64 rows.
//   Each ds_read_b128 (wave-broadcast, conflict-free) feeds 8 FMAs.
// ---------------------------------------------------------------------------
struct __align__(16) K1Smem {
    float rW2t[Hn][68];      // transposed rW2 [k2][k], padded rows, 16B-aligned
    float wh2[JT][68];       // w-scaled LN'd h2 for the current j-tile
    float rW1s[Hn], rb1s[Hn], rg1s[Hn], rb2s[Hn], rg2s[Hn];
    float pS1[2][JT], pS2[2][JT];   // h2-LN partial stats per half
    float wS[JT];            // weight w per row of the tile
    float accA[256], accB[256];     // final cross-thread combine
    int   atomsS[Nn];
};

__global__ __launch_bounds__(256, 2)
void k1_neighbor_feats(const int* __restrict__ atoms,
                       const float* __restrict__ rel_dist,
                       const int* __restrict__ adj_mat,
                       const int* __restrict__ mask,
                       const float* __restrict__ soft,
                       const float* __restrict__ neigh_tab,
                       const float* __restrict__ rW1, const float* __restrict__ rb1,
                       const float* __restrict__ rg1,
                       const float* __restrict__ rW2, const float* __restrict__ rb2,
                       const float* __restrict__ rg2,
                       const float* __restrict__ rW3, const float* __restrict__ rb3,
                       float* __restrict__ nf)
{
    __shared__ K1Smem sm;
    const int t  = threadIdx.x;
    const int bi = blockIdx.x;      // b*N + i
    const int b  = bi >> 9;
    const int i  = bi & 511;

    // ---- stage weights ----
    for (int idx = t; idx < Hn * Hn; idx += 256) {
        sm.rW2t[idx & 63][idx >> 6] = rW2[idx];   // rW2t[k2][k] = rW2[k][k2]
    }
    if (t < Hn) {
        sm.rW1s[t] = rW1[t];
        sm.rb1s[t] = rb1[t];
        sm.rg1s[t] = rg1[t];
        sm.rb2s[t] = rb2[t];
        sm.rg2s[t] = rg2[t];
    }
    for (int j = t; j < Nn; j += 256) sm.atomsS[j] = atoms[b * Nn + j];

    // phase-A mapping
    const int jloc = t & 127;
    const int half = t >> 7;
    // phase-B mapping
    const int d2 = t & 63;          // output column pair {2*d2, 2*d2+1}
    const int kh = (t >> 6) & 1;    // k-slice
    const int jh = t >> 7;          // row-half
    const float2 rb3v  = *(const float2*)&rb3[2 * d2];
    const float  rb3e0 = (kh == 0) ? rb3v.x : 0.0f;   // bias counted once per (j,d)
    const float  rb3e1 = (kh == 0) ? rb3v.y : 0.0f;
    const int rowbase = bi * Nn;

    float acc0 = 0.0f, acc1 = 0.0f;
    __syncthreads();

    for (int jt = 0; jt < NT; ++jt) {
        const int jme = jt * JT + jloc;

        // ---- phase A ----
        const float dist = rel_dist[rowbase + jme];
        const int   adjv = adj_mat[rowbase + jme];
        const int   mk   = mask[b * Nn + jme];
        const float w = (adjv != 0 && mk != 0 && jme != i) ? soft[rowbase + jme] : 0.0f;

        // layer 1: silu(dist*rW1 + rb1) then LN(rg1)  (full 64, both halves)
        float h1n[Hn];
        float s1 = 0.f, s2 = 0.f;
        #pragma unroll
        for (int k = 0; k < Hn; ++k) {
            const float v = silu_f(dist * sm.rW1s[k] + sm.rb1s[k]);
            h1n[k] = v; s1 += v; s2 += v * v;
        }
        float m  = s1 * (1.0f / 64.0f);
        float vr = s2 * (1.0f / 64.0f) - m * m;
        float rs = rsqrtf(vr + 1e-5f);
        #pragma unroll
        for (int k = 0; k < Hn; ++k) h1n[k] = (h1n[k] - m) * rs * sm.rg1s[k];

        // layer 2 (my 32-wide half of k2): silu(h1n @ rW2 + rb2)
        float h2[32];
        float t1 = 0.f, t2 = 0.f;
        #pragma unroll
        for (int k2 = 0; k2 < 32; ++k2) {
            const int kk2 = half * 32 + k2;
            float p0 = 0.f, p1 = 0.f, p2 = 0.f, p3 = 0.f;
            #pragma unroll
            for (int k = 0; k < Hn; k += 4) {
                const float4 wv = *(const float4*)&sm.rW2t[kk2][k];  // broadcast
                p0 += h1n[k + 0] * wv.x;
                p1 += h1n[k + 1] * wv.y;
                p2 += h1n[k + 2] * wv.z;
                p3 += h1n[k + 3] * wv.w;
            }
            const float v = silu_f((p0 + p1) + (p2 + p3) + sm.rb2s[kk2]);
            h2[k2] = v; t1 += v; t2 += v * v;
        }
        // combine LN stats across the half-pair
        sm.pS1[half][jloc] = t1;
        sm.pS2[half][jloc] = t2;
        if (half == 0) sm.wS[jloc] = w;
        __syncthreads();
        const float T1 = sm.pS1[0][jloc] + sm.pS1[1][jloc];
        const float T2 = sm.pS2[0][jloc] + sm.pS2[1][jloc];
        m  = T1 * (1.0f / 64.0f);
        vr = T2 * (1.0f / 64.0f) - m * m;
        rs = rsqrtf(vr + 1e-5f);
        #pragma unroll
        for (int k2 = 0; k2 < 32; k2 += 4) {
            const int kk2 = half * 32 + k2;
            float4 ov;
            ov.x = w * ((h2[k2 + 0] - m) * rs * sm.rg2s[kk2 + 0]);
            ov.y = w * ((h2[k2 + 1] - m) * rs * sm.rg2s[kk2 + 1]);
            ov.z = w * ((h2[k2 + 2] - m) * rs * sm.rg2s[kk2 + 2]);
            ov.w = w * ((h2[k2 + 3] - m) * rs * sm.rg2s[kk2 + 3]);
            *(float4*)&sm.wh2[jloc][kk2] = ov;
        }
        __syncthreads();

        // ---- phase B: contraction over the tile ----
        // (h1n/h2 dead here; rW3 slice loaded now to keep peak VGPR low)
        float rw3a[32], rw3b[32];
        #pragma unroll
        for (int k = 0; k < 32; ++k) {
            const float2 rv = *(const float2*)&rW3[(kh * 32 + k) * Dn + 2 * d2];
            rw3a[k] = rv.x; rw3b[k] = rv.y;
        }
        #pragma unroll 4
        for (int jj = 0; jj < 64; ++jj) {
            const int lr = jh * 64 + jj;
            const int j  = jt * JT + lr;
            float pa0 = 0.f, pa1 = 0.f, pa2 = 0.f, pa3 = 0.f;
            float pb0 = 0.f, pb1 = 0.f, pb2 = 0.f, pb3 = 0.f;
            #pragma unroll
            for (int k = 0; k < 32; k += 4) {
                const float4 hv = *(const float4*)&sm.wh2[lr][kh * 32 + k];  // broadcast
                pa0 += hv.x * rw3a[k + 0];
                pa1 += hv.y * rw3a[k + 1];
                pa2 += hv.z * rw3a[k + 2];
                pa3 += hv.w * rw3a[k + 3];
                pb0 += hv.x * rw3b[k + 0];
                pb1 += hv.y * rw3b[k + 1];
                pb2 += hv.z * rw3b[k + 2];
                pb3 += hv.w * rw3b[k + 3];
            }
            const float  wj = sm.wS[lr];
            const float2 nv = *(const float2*)&neigh_tab[sm.atomsS[j] * Dn + 2 * d2];
            acc0 += (((pa0 + pa1) + (pa2 + pa3)) + wj * rb3e0) * nv.x;
            acc1 += (((pb0 + pb1) + (pb2 + pb3)) + wj * rb3e1) * nv.y;
        }
        __syncthreads();   // protect wh2/pS/wS for next tile
    }

    // ---- final cross-thread combine: out d gets 4 partials ----
    sm.accA[t] = acc0;
    sm.accB[t] = acc1;
    __syncthreads();
    if (t < Dn) {
        const int  dd2 = t >> 1;
        const bool odd = (t & 1) != 0;
        float r = 0.f;
        #pragma unroll
        for (int q = 0; q < 4; ++q) {
            const int src = dd2 + 64 * (q & 1) + 128 * (q >> 1);  // d2 + 64*kh + 128*jh
            r += odd ? sm.accB[src] : sm.accA[src];
        }
        nf[bi * Dn + t] = r;
    }
}

// ---------------------------------------------------------------------------
// Kernel 2: node MLP.  x = [embeds, nf] (256) -> Linear -> LN -> silu -> Linear
// One block per (b,i); 128 threads (one per output d).
// ---------------------------------------------------------------------------
__global__ __launch_bounds__(128)
void k2_node_mlp(const int* __restrict__ atoms,
                 const float* __restrict__ atom_tab,
                 const float* __restrict__ nf,
                 const float* __restrict__ nW1, const float* __restrict__ nb1,
                 const float* __restrict__ ng,
                 const float* __restrict__ nW2, const float* __restrict__ nb2,
                 float* __restrict__ out)
{
    __shared__ float xs[256];
    __shared__ float r1[2], r2[2];
    __shared__ float x2[128];

    const int t  = threadIdx.x;
    const int bi = blockIdx.x;
    const int a  = atoms[bi];

    xs[t]       = atom_tab[a * Dn + t];
    xs[128 + t] = nf[bi * Dn + t];
    __syncthreads();

    float p0 = 0.f, p1 = 0.f, p2 = 0.f, p3 = 0.f;
    #pragma unroll 4
    for (int c = 0; c < 256; c += 4) {
        p0 += xs[c + 0] * nW1[(c + 0) * Dn + t];
        p1 += xs[c + 1] * nW1[(c + 1) * Dn + t];
        p2 += xs[c + 2] * nW1[(c + 2) * Dn + t];
        p3 += xs[c + 3] * nW1[(c + 3) * Dn + t];
    }
    const float s = (p0 + p1) + (p2 + p3) + nb1[t];

    // LN over 128 (2 waves): wave shuffle reduce + LDS combine
    float a1 = s, a2 = s * s;
    #pragma unroll
    for (int off = 32; off > 0; off >>= 1) {
        a1 += __shfl_down(a1, off);
        a2 += __shfl_down(a2, off);
    }
    const int wid = t >> 6;
    if ((t & 63) == 0) { r1[wid] = a1; r2[wid] = a2; }
    __syncthreads();
    const float S1 = r1[0] + r1[1];
    const float S2 = r2[0] + r2[1];
    const float m  = S1 * (1.0f / 128.0f);
    const float vr = S2 * (1.0f / 128.0f) - m * m;
    const float rs = rsqrtf(vr + 1e-5f);
    const float y  = silu_f((s - m) * rs * ng[t]);   // LN first, THEN silu

    x2[t] = y;
    __syncthreads();

    float q0 = 0.f, q1 = 0.f, q2 = 0.f, q3 = 0.f;
    #pragma unroll 4
    for (int c = 0; c < 128; c += 4) {
        q0 += x2[c + 0] * nW2[(c + 0) * Dn + t];
        q1 += x2[c + 1] * nW2[(c + 1) * Dn + t];
        q2 += x2[c + 2] * nW2[(c + 2) * Dn + t];
        q3 += x2[c + 3] * nW2[(c + 3) * Dn + t];
    }
    out[bi * Dn + t] = (q0 + q1) + (q2 + q3) + nb2[t];
}

// ---------------------------------------------------------------------------
extern "C" void kernel_launch(void* const* d_in, const int* in_sizes, int n_in,
                              void* d_out, int out_size, void* d_ws, size_t ws_size,
                              hipStream_t stream)
{
    (void)in_sizes; (void)n_in; (void)out_size; (void)ws_size;

    const int*   atoms = (const int*)d_in[0];
    const float* rel   = (const float*)d_in[1];
    const int*   adj   = (const int*)d_in[2];
    const int*   mask  = (const int*)d_in[3];
    const float* soft  = (const float*)d_in[4];
    const float* atab  = (const float*)d_in[5];
    const float* ntab  = (const float*)d_in[6];
    const float* rW1   = (const float*)d_in[7];
    const float* rb1   = (const float*)d_in[8];
    const float* rg1   = (const float*)d_in[9];
    const float* rW2   = (const float*)d_in[10];
    const float* rb2   = (const float*)d_in[11];
    const float* rg2   = (const float*)d_in[12];
    const float* rW3   = (const float*)d_in[13];
    const float* rb3   = (const float*)d_in[14];
    const float* nW1   = (const float*)d_in[15];
    const float* nb1   = (const float*)d_in[16];
    const float* ng    = (const float*)d_in[17];
    const float* nW2   = (const float*)d_in[18];
    const float* nb2   = (const float*)d_in[19];

    float* nf  = (float*)d_ws;      // [B*N, D] neighbor feats scratch (1 MB)
    float* out = (float*)d_out;

    hipLaunchKernelGGL(k1_neighbor_feats, dim3(Bn * Nn), dim3(256), 0, stream,
                       atoms, rel, adj, mask, soft, ntab,
                       rW1, rb1, rg1, rW2, rb2, rg2, rW3, rb3, nf);
    hipLaunchKernelGGL(k2_node_mlp, dim3(Bn * Nn), dim3(128), 0, stream,
                       atoms, atab, nf, nW1, nb1, ng, nW2, nb2, out);
}